// Round 12
// baseline (175.619 us; speedup 1.0000x reference)
//
#include <hip/hip_runtime.h>

// SparseMatmul3D: out[b,n,m] = sum_k x[b,n,k] * y[b,m,k]
// B=4, N=M=4096, D=64, fp32 in/out. Write-bound (268 MB out, floor ~38us @7TB/s).
// R1:  128x128 direct stores      -> 89.7 us (~3.0 TB/s)
// R2:  LDS full-line stores       -> 94.5 us
// R3/R5: 16-32-row slabs          -> 163/132 us
// R7:  16x512 LDS 1KB runs        -> 143 us
// R8:  64x256, stores-at-end      -> 91.2 us
// R9:  R8 + NT                    -> 89.5 us (NT neutral)
// R10: 16x4096 dense burst        -> 156 us (confounded: launch_bounds spill/occ)
// R11: 256x64                     -> 92.4 us (aspect flat)
//   Every structure pins at ~3 TB/s; fill does 7 TB/s. Never measured: pure
//   stores in our pattern.
// R12: INSTRUMENTATION ROUND. probe_linear (fill-mimic sweep, 268MB) +
//   probe_tile (exact R8 store pattern, pure stores) + real R8 kernel.
//   dur_us ~173 -> structure guilty; ~218 -> tile pattern guilty; ~270 -> both.

#define BATCH 4
#define NN 4096
#define MM 4096
#define DD 64

typedef __attribute__((ext_vector_type(8))) short bf16x8;
typedef __attribute__((ext_vector_type(4))) float f32x4;

__device__ __forceinline__ unsigned short f2bf(float f) {
    unsigned u = __builtin_bit_cast(unsigned, f);
    u += 0x7FFFu + ((u >> 16) & 1u);   // round-to-nearest-even
    return (unsigned short)(u >> 16);
}

__device__ __forceinline__ bf16x8 load8_bf16(const float* __restrict__ p) {
    f32x4 v0 = *reinterpret_cast<const f32x4*>(p);
    f32x4 v1 = *reinterpret_cast<const f32x4*>(p + 4);
    bf16x8 r;
    r[0] = (short)f2bf(v0[0]); r[1] = (short)f2bf(v0[1]);
    r[2] = (short)f2bf(v0[2]); r[3] = (short)f2bf(v0[3]);
    r[4] = (short)f2bf(v1[0]); r[5] = (short)f2bf(v1[1]);
    r[6] = (short)f2bf(v1[2]); r[7] = (short)f2bf(v1[3]);
    return r;
}

// ---- probe 1: fill-mimic linear sweep (268 MB, overwritten by real kernel) ----
__global__ __launch_bounds__(256) void
probe_linear_kernel(float* __restrict__ out) {
    // 67108864 floats = 16777216 f32x4. 2048 blocks * 256 thr = 524288 lanes,
    // 32 grid-stride iterations; dense sliding window like fillBufferAligned.
    f32x4* __restrict__ p = reinterpret_cast<f32x4*>(out);
    const unsigned base = blockIdx.x * 256u + threadIdx.x;
    const f32x4 v = (f32x4){0.f, 0.f, 0.f, 0.f};
#pragma unroll
    for (int it = 0; it < 32; ++it)
        p[(size_t)it * 524288u + base] = v;
}

// ---- probe 2: exact R8 store addressing, pure stores ----
__global__ __launch_bounds__(256, 4) void
probe_tile_kernel(float* __restrict__ out) {
    const int bid = blockIdx.x;            // [0,4096)
    const int b   = bid >> 10;
    const int ntl = (bid >> 4) & 63;
    const int mc  = bid & 15;

    const int w    = threadIdx.x >> 6;
    const int lane = threadIdx.x & 63;
    const int n0   = ntl * 64;
    const int m0   = (mc * 4 + w) * 64;

    const int row16 = lane & 15;
    const int kgrp  = lane >> 4;

    const f32x4 v = (f32x4){0.f, 0.f, 0.f, 0.f};
    float* __restrict__ ob = out + (size_t)b * NN * MM;
#pragma unroll
    for (int j = 0; j < 4; ++j) {
        const int n = n0 + j * 16 + row16;
        float* orow = ob + (size_t)n * MM;
#pragma unroll
        for (int i = 0; i < 4; ++i)
            *reinterpret_cast<f32x4*>(orow + m0 + i * 16 + kgrp * 4) = v;
    }
}

// ---- real kernel: R8 verbatim ----
__global__ __launch_bounds__(256, 4) void
SparseMatmul3D_36155034698289_kernel(const float* __restrict__ x,
                                     const float* __restrict__ y,
                                     float* __restrict__ out) {
    const int bid = blockIdx.x;            // [0,4096)
    const int b   = bid >> 10;
    const int ntl = (bid >> 4) & 63;
    const int mc  = bid & 15;

    const int w    = threadIdx.x >> 6;
    const int lane = threadIdx.x & 63;
    const int n0   = ntl * 64;
    const int m0   = (mc * 4 + w) * 64;

    const int row16 = lane & 15;
    const int kgrp  = lane >> 4;

    const float* __restrict__ xb = x + (size_t)b * NN * DD;
    const float* __restrict__ yb = y + (size_t)b * MM * DD;

    bf16x8 bfrag[4][2];
#pragma unroll
    for (int j = 0; j < 4; ++j) {
        const float* p = xb + (size_t)(n0 + j * 16 + row16) * DD + kgrp * 8;
        bfrag[j][0] = load8_bf16(p);
        bfrag[j][1] = load8_bf16(p + 32);
    }

    f32x4 acc[4][4];
#pragma unroll
    for (int i = 0; i < 4; ++i)
#pragma unroll
        for (int j = 0; j < 4; ++j)
            acc[i][j] = (f32x4){0.f, 0.f, 0.f, 0.f};

#pragma unroll
    for (int h = 0; h < 2; ++h) {
        bf16x8 af[2][2];
#pragma unroll
        for (int i = 0; i < 2; ++i) {
            const float* p = yb + (size_t)(m0 + (h * 2 + i) * 16 + row16) * DD + kgrp * 8;
            af[i][0] = load8_bf16(p);
            af[i][1] = load8_bf16(p + 32);
        }
#pragma unroll
        for (int ks = 0; ks < 2; ++ks)
#pragma unroll
            for (int i = 0; i < 2; ++i)
#pragma unroll
                for (int j = 0; j < 4; ++j)
                    acc[h * 2 + i][j] = __builtin_amdgcn_mfma_f32_16x16x32_bf16(
                        af[i][ks], bfrag[j][ks], acc[h * 2 + i][j], 0, 0, 0);
    }

    float* __restrict__ ob = out + (size_t)b * NN * MM;
#pragma unroll
    for (int j = 0; j < 4; ++j) {
        const int n = n0 + j * 16 + row16;
        float* orow = ob + (size_t)n * MM;
#pragma unroll
        for (int i = 0; i < 4; ++i)
            *reinterpret_cast<f32x4*>(orow + m0 + i * 16 + kgrp * 4) = acc[i][j];
    }
}

extern "C" void kernel_launch(void* const* d_in, const int* in_sizes, int n_in,
                              void* d_out, int out_size, void* d_ws, size_t ws_size,
                              hipStream_t stream) {
    const float* x = (const float*)d_in[0];
    const float* y = (const float*)d_in[1];
    float* out = (float*)d_out;

    // Probes write d_out first (overwritten by the real kernel afterwards).
    probe_linear_kernel<<<dim3(2048), dim3(256), 0, stream>>>(out);
    probe_tile_kernel<<<dim3(4096), dim3(256), 0, stream>>>(out);
    SparseMatmul3D_36155034698289_kernel<<<dim3(4096), dim3(256), 0, stream>>>(x, y, out);
}

// Round 13
// 97.315 us; speedup vs baseline: 1.8046x; 1.8046x over previous
//
#include <hip/hip_runtime.h>

// SparseMatmul3D: out[b,n,m] = sum_k x[b,n,k] * y[b,m,k]
// B=4, N=M=4096, D=64, fp32 in/out. Write-bound (268 MB out, floor ~38us @7TB/s).
// R1-R11: every tiling/ordering/NT/density variant pins at ~90us (~3 TB/s).
// R12 probes: pure stores in EXACT R8 pattern -> ~7 TB/s. Pattern innocent.
//   => cap comes from wave structure: one store burst at end-of-wave, waves
//      convoy in phase -> store path starved between bursts.
// R13: pipelined persistent waves. Wave = 64-row n-band x 4 m-adjacent 64x64
//   tiles. Per iter: cvt(t) -> prefetch-loads(t+1) -> MFMA(t) -> stores(t);
//   loads issued BEFORE stores so wait-for-loads = vmcnt(16), stores stay in
//   flight across iterations. Stores issued continuously, desynchronized.

#define BATCH 4
#define NN 4096
#define MM 4096
#define DD 64

typedef __attribute__((ext_vector_type(8))) short bf16x8;
typedef __attribute__((ext_vector_type(4))) float f32x4;

__device__ __forceinline__ unsigned short f2bf(float f) {
    unsigned u = __builtin_bit_cast(unsigned, f);
    u += 0x7FFFu + ((u >> 16) & 1u);   // round-to-nearest-even
    return (unsigned short)(u >> 16);
}

__device__ __forceinline__ bf16x8 cvt8(f32x4 v0, f32x4 v1) {
    bf16x8 r;
    r[0] = (short)f2bf(v0[0]); r[1] = (short)f2bf(v0[1]);
    r[2] = (short)f2bf(v0[2]); r[3] = (short)f2bf(v0[3]);
    r[4] = (short)f2bf(v1[0]); r[5] = (short)f2bf(v1[1]);
    r[6] = (short)f2bf(v1[2]); r[7] = (short)f2bf(v1[3]);
    return r;
}

__global__ __launch_bounds__(256) void
SparseMatmul3D_36155034698289_kernel(const float* __restrict__ x,
                                     const float* __restrict__ y,
                                     float* __restrict__ out) {
    const int g    = blockIdx.x * 4 + (threadIdx.x >> 6);  // wave id [0,4096)
    const int b    = g >> 10;              // batch
    const int ntl  = (g >> 4) & 63;        // 64-row n-band
    const int mg   = g & 15;               // 256-wide m-group (fastest)
    const int lane = threadIdx.x & 63;
    const int row16 = lane & 15;
    const int kgrp  = lane >> 4;
    const int n0    = ntl * 64;
    const int mbase = mg * 256;

    const float* __restrict__ xb = x + (size_t)b * NN * DD;
    const float* __restrict__ yb = y + (size_t)b * MM * DD;

    // B operand = x rows (n side), loaded once per wave
    bf16x8 bfrag[4][2];
#pragma unroll
    for (int j = 0; j < 4; ++j) {
        const float* p = xb + (size_t)(n0 + j * 16 + row16) * DD + kgrp * 8;
        f32x4 v0 = *reinterpret_cast<const f32x4*>(p);
        f32x4 v1 = *reinterpret_cast<const f32x4*>(p + 4);
        f32x4 v2 = *reinterpret_cast<const f32x4*>(p + 32);
        f32x4 v3 = *reinterpret_cast<const f32x4*>(p + 36);
        bfrag[j][0] = cvt8(v0, v1);
        bfrag[j][1] = cvt8(v2, v3);
    }

    // Raw y prefetch buffer for one 64x64 tile (16 x f32x4)
    f32x4 yraw[4][4];

    // Prologue: load tile 0 raw
#pragma unroll
    for (int mt = 0; mt < 4; ++mt) {
        const float* p = yb + (size_t)(mbase + mt * 16 + row16) * DD + kgrp * 8;
        yraw[mt][0] = *reinterpret_cast<const f32x4*>(p);
        yraw[mt][1] = *reinterpret_cast<const f32x4*>(p + 4);
        yraw[mt][2] = *reinterpret_cast<const f32x4*>(p + 32);
        yraw[mt][3] = *reinterpret_cast<const f32x4*>(p + 36);
    }

    float* __restrict__ ob = out + (size_t)b * NN * MM;

#pragma unroll
    for (int it = 0; it < 4; ++it) {
        const int m0 = mbase + it * 64;

        // 1. consume raw -> bf16 A-fragments (frees yraw)
        bf16x8 af[4][2];
#pragma unroll
        for (int mt = 0; mt < 4; ++mt) {
            af[mt][0] = cvt8(yraw[mt][0], yraw[mt][1]);
            af[mt][1] = cvt8(yraw[mt][2], yraw[mt][3]);
        }

        // 2. issue next tile's raw loads (BEFORE this tile's stores, so the
        //    pipeline wait is vmcnt(16) and stores stay in flight)
        if (it < 3) {
            const int mn = mbase + (it + 1) * 64;
#pragma unroll
            for (int mt = 0; mt < 4; ++mt) {
                const float* p = yb + (size_t)(mn + mt * 16 + row16) * DD + kgrp * 8;
                yraw[mt][0] = *reinterpret_cast<const f32x4*>(p);
                yraw[mt][1] = *reinterpret_cast<const f32x4*>(p + 4);
                yraw[mt][2] = *reinterpret_cast<const f32x4*>(p + 32);
                yraw[mt][3] = *reinterpret_cast<const f32x4*>(p + 36);
            }
        }

        // 3. MFMA this tile
        f32x4 acc[4][4];
#pragma unroll
        for (int i = 0; i < 4; ++i)
#pragma unroll
            for (int j = 0; j < 4; ++j) {
                acc[i][j] = __builtin_amdgcn_mfma_f32_16x16x32_bf16(
                    af[i][0], bfrag[j][0], (f32x4){0.f, 0.f, 0.f, 0.f}, 0, 0, 0);
                acc[i][j] = __builtin_amdgcn_mfma_f32_16x16x32_bf16(
                    af[i][1], bfrag[j][1], acc[i][j], 0, 0, 0);
            }

        // 4. store this tile (D layout: col=lane&15=n; row=kgrp*4+reg=m)
#pragma unroll
        for (int j = 0; j < 4; ++j) {
            float* orow = ob + (size_t)(n0 + j * 16 + row16) * MM;
#pragma unroll
            for (int i = 0; i < 4; ++i)
                *reinterpret_cast<f32x4*>(orow + m0 + i * 16 + kgrp * 4) = acc[i][j];
        }
    }
}

extern "C" void kernel_launch(void* const* d_in, const int* in_sizes, int n_in,
                              void* d_out, int out_size, void* d_ws, size_t ws_size,
                              hipStream_t stream) {
    const float* x = (const float*)d_in[0];
    const float* y = (const float*)d_in[1];
    float* out = (float*)d_out;

    dim3 grid(1024);
    dim3 block(256);
    SparseMatmul3D_36155034698289_kernel<<<grid, block, 0, stream>>>(x, y, out);
}

// Round 14
// 96.813 us; speedup vs baseline: 1.8140x; 1.0052x over previous
//
#include <hip/hip_runtime.h>

// SparseMatmul3D: out[b,n,m] = sum_k x[b,n,k] * y[b,m,k]
// B=4, N=M=4096, D=64, fp32 in/out. Write-bound (268 MB out, floor ~38us @7TB/s).
// R1-R11: every tiling/order/NT/density/aspect variant pins at ~90us (~3 TB/s).
// R12: probe_tile (EXACT R8 store pattern, pure stores) -> ~6.5 TB/s. Pattern OK.
// R13: per-wave software pipeline -> 97us. Per-wave structure not the lever.
//   Invariant: waves that BOTH load and store cap at 3 TB/s (per-wave in-order
//   vmem queue couples next loads to store-ack latency); pure-store waves hit 7.
// R14: producer-consumer role split. 4 compute waves (load+MFMA+ds_write, no
//   global stores) + 4 writer waves (ds_read+store only == probe_tile stream),
//   double-buffered 2x64KB LDS, persistent 256 blocks x 16 tiles.

#define BATCH 4
#define NN 4096
#define MM 4096
#define DD 64
#define TPB 16   // tiles per block

typedef __attribute__((ext_vector_type(8))) short bf16x8;
typedef __attribute__((ext_vector_type(4))) float f32x4;

__device__ __forceinline__ unsigned short f2bf(float f) {
    unsigned u = __builtin_bit_cast(unsigned, f);
    u += 0x7FFFu + ((u >> 16) & 1u);   // round-to-nearest-even
    return (unsigned short)(u >> 16);
}

__device__ __forceinline__ bf16x8 load8_bf16(const float* __restrict__ p) {
    f32x4 v0 = *reinterpret_cast<const f32x4*>(p);
    f32x4 v1 = *reinterpret_cast<const f32x4*>(p + 4);
    bf16x8 r;
    r[0] = (short)f2bf(v0[0]); r[1] = (short)f2bf(v0[1]);
    r[2] = (short)f2bf(v0[2]); r[3] = (short)f2bf(v0[3]);
    r[4] = (short)f2bf(v1[0]); r[5] = (short)f2bf(v1[1]);
    r[6] = (short)f2bf(v1[2]); r[7] = (short)f2bf(v1[3]);
    return r;
}

__global__ __launch_bounds__(512, 1) void
SparseMatmul3D_36155034698289_kernel(const float* __restrict__ x,
                                     const float* __restrict__ y,
                                     float* __restrict__ out) {
    __shared__ float lds[2][64 * 256];   // 128 KB: double-buffered 64n x 256m tile

    const int tid   = threadIdx.x;
    const int w     = tid >> 6;          // 0..7
    const int lane  = tid & 63;
    const int row16 = lane & 15;
    const int kgrp  = lane >> 4;
    const bool writer = (w >= 4);
    const int  sw     = w & 3;           // role-local wave index
    const int  mwave  = sw * 64;         // this wave's 64-wide m-window in tile

#pragma unroll 1
    for (int g = 0; g <= TPB; ++g) {
        if (!writer && g < TPB) {
            // ---- compute tile g into lds[g&1] (R8-proven math) ----
            const int t   = blockIdx.x + (g << 8);   // tile id [0,4096)
            const int b   = t >> 10;
            const int ntl = (t >> 4) & 63;
            const int mc  = t & 15;
            const int n0    = ntl * 64;
            const int m0    = mc * 256 + mwave;

            const float* __restrict__ xb = x + (size_t)b * NN * DD;
            const float* __restrict__ yb = y + (size_t)b * MM * DD;

            bf16x8 bfrag[4][2];
#pragma unroll
            for (int j = 0; j < 4; ++j) {
                const float* p = xb + (size_t)(n0 + j * 16 + row16) * DD + kgrp * 8;
                bfrag[j][0] = load8_bf16(p);
                bfrag[j][1] = load8_bf16(p + 32);
            }

            f32x4 acc[4][4];
#pragma unroll
            for (int i = 0; i < 4; ++i)
#pragma unroll
                for (int j = 0; j < 4; ++j)
                    acc[i][j] = (f32x4){0.f, 0.f, 0.f, 0.f};

#pragma unroll
            for (int h = 0; h < 2; ++h) {
                bf16x8 af[2][2];
#pragma unroll
                for (int i = 0; i < 2; ++i) {
                    const float* p = yb + (size_t)(m0 + (h * 2 + i) * 16 + row16) * DD + kgrp * 8;
                    af[i][0] = load8_bf16(p);
                    af[i][1] = load8_bf16(p + 32);
                }
#pragma unroll
                for (int ks = 0; ks < 2; ++ks)
#pragma unroll
                    for (int i = 0; i < 2; ++i)
#pragma unroll
                        for (int j = 0; j < 4; ++j)
                            acc[h * 2 + i][j] = __builtin_amdgcn_mfma_f32_16x16x32_bf16(
                                af[i][ks], bfrag[j][ks], acc[h * 2 + i][j], 0, 0, 0);
            }

            // stage into LDS; XOR swizzle (16B granule) -> 2-way max (free)
            float* __restrict__ buf = lds[g & 1];
#pragma unroll
            for (int j = 0; j < 4; ++j) {
                const int nl = j * 16 + row16;
#pragma unroll
                for (int i = 0; i < 4; ++i) {
                    const int ml = mwave + i * 16 + kgrp * 4;
                    *reinterpret_cast<f32x4*>(&buf[nl * 256 + (ml ^ ((nl & 7) << 2))]) = acc[i][j];
                }
            }
        } else if (writer && g > 0) {
            // ---- drain tile g-1 from lds[(g-1)&1]: probe_tile-identical stream ----
            const int t   = blockIdx.x + ((g - 1) << 8);
            const int b   = t >> 10;
            const int ntl = (t >> 4) & 63;
            const int mc  = t & 15;
            const int n0    = ntl * 64;
            const int mbase = mc * 256;

            const float* __restrict__ buf = lds[(g - 1) & 1];
            float* __restrict__ ob = out + (size_t)b * NN * MM;
#pragma unroll
            for (int j = 0; j < 4; ++j) {
                const int nl = j * 16 + row16;
                float* orow = ob + (size_t)(n0 + nl) * MM + mbase;
#pragma unroll
                for (int i = 0; i < 4; ++i) {
                    const int ml = mwave + i * 16 + kgrp * 4;
                    f32x4 v = *reinterpret_cast<const f32x4*>(
                        &buf[nl * 256 + (ml ^ ((nl & 7) << 2))]);
                    *reinterpret_cast<f32x4*>(orow + ml) = v;
                }
            }
        }
        if (g < TPB) __syncthreads();
    }
}

extern "C" void kernel_launch(void* const* d_in, const int* in_sizes, int n_in,
                              void* d_out, int out_size, void* d_ws, size_t ws_size,
                              hipStream_t stream) {
    const float* x = (const float*)d_in[0];
    const float* y = (const float*)d_in[1];
    float* out = (float*)d_out;

    dim3 grid(256);
    dim3 block(512);
    SparseMatmul3D_36155034698289_kernel<<<grid, block, 0, stream>>>(x, y, out);
}